// Round 6
// baseline (2681.105 us; speedup 1.0000x reference)
//
#include <hip/hip_runtime.h>
#include <hip/hip_bf16.h>
#include <cstdint>

// B=32, L=256, D=256, H=256, E=8, NL=4, K=4; 256 sequences total.
// R6: 16 blocks x 256 thr (4 waves). Each block owns 16 sequences = the 16
// MFMA B-columns (W_hh/W_ih shared across sequences -> zero column waste).
// Wave w owns h-rows [64w,64w+64) = 4 m-tiles; whh resident in VGPRs.
// Inter-layer GEMM maps m=h so D-regs (pre[4][8]) feed the scan accumulator
// directly; x/ys live in ONE in-place global fp16 buffer [n][l][d].

typedef _Float16 f16;
typedef _Float16 f16x8 __attribute__((ext_vector_type(8)));
typedef _Float16 f16x4 __attribute__((ext_vector_type(4)));
typedef float f32x4 __attribute__((ext_vector_type(4)));

__device__ __forceinline__ float tanh_fast(float x) {
  float e = __expf(2.f * x);
  return fmaf(-2.f, __builtin_amdgcn_rcpf(e + 1.f), 1.f);
}

// ---------------- LayerNorm over D for each (b,l) row ----------------
__global__ __launch_bounds__(256) void ln_kernel(
    const float* __restrict__ x, const float* __restrict__ g,
    const float* __restrict__ beta, float* __restrict__ out)
{
  const int row = blockIdx.x;
  const int t = threadIdx.x;
  const float v = x[row * 256 + t];
  __shared__ float red[4];
  float s = v;
  #pragma unroll
  for (int off = 32; off > 0; off >>= 1) s += __shfl_xor(s, off);
  if ((t & 63) == 0) red[t >> 6] = s;
  __syncthreads();
  const float mean = (red[0] + red[1] + red[2] + red[3]) * (1.f / 256.f);
  const float d = v - mean;
  float sq = d * d;
  #pragma unroll
  for (int off = 32; off > 0; off >>= 1) sq += __shfl_xor(sq, off);
  __syncthreads();
  if ((t & 63) == 0) red[t >> 6] = sq;
  __syncthreads();
  const float var = (red[0] + red[1] + red[2] + red[3]) * (1.f / 256.f);
  out[row * 256 + t] = d * rsqrtf(var + 1e-5f) * g[t] + beta[t];
}

// ---------------- Depthwise causal conv1d (K=4, left pad 3) ----------------
__global__ __launch_bounds__(256) void conv_kernel(
    const float* __restrict__ ln, const float* __restrict__ w,
    const float* __restrict__ cb, float* __restrict__ out)
{
  const int l = blockIdx.x & 255;
  const int b = blockIdx.x >> 8;
  const int d = threadIdx.x;
  const float4 wv = *(const float4*)(w + d * 4);
  const float wk[4] = {wv.x, wv.y, wv.z, wv.w};
  float acc = cb[d];
  #pragma unroll
  for (int k = 0; k < 4; ++k) {
    const int ls = l - 3 + k;
    if (ls >= 0) acc = fmaf(ln[((b << 8) + ls) * 256 + d], wk[k], acc);
  }
  out[((b << 8) + l) * 256 + d] = acc;
}

// ---------------- x16[n][l][d] = f16(conv[b][l][d] * r[e][d]) ----------------
__global__ __launch_bounds__(256) void xprep_kernel(
    const float* __restrict__ cvb, const float* __restrict__ rr,
    f16* __restrict__ x16)
{
  const int u = blockIdx.x * 256 + threadIdx.x;   // 2,097,152 units
  const int dg = u & 31, row = u >> 5;            // row = n*256 + l
  const int n = row >> 8, l = row & 255;
  const int b = n >> 3, e = n & 7;
  const int d0 = dg * 8;
  const float* src = cvb + (size_t)(((b << 8) + l) << 8) + d0;
  const float* rp = rr + e * 256 + d0;
  const f32x4 a = *(const f32x4*)src * *(const f32x4*)rp;
  const f32x4 c = *(const f32x4*)(src + 4) * *(const f32x4*)(rp + 4);
  f16x8 o;
  o[0]=(f16)a.x; o[1]=(f16)a.y; o[2]=(f16)a.z; o[3]=(f16)a.w;
  o[4]=(f16)c.x; o[5]=(f16)c.y; o[6]=(f16)c.z; o[7]=(f16)c.w;
  *(f16x8*)(x16 + (size_t)row * 256 + d0) = o;
}

// ---------------- One-time fp32 -> fp16 weight conversion ----------------
__global__ __launch_bounds__(512) void wcvt_kernel(
    const float* __restrict__ Wi, const float* __restrict__ Wh,
    f16* __restrict__ wi16, f16* __restrict__ wh16)
{
  const int i = blockIdx.x * 512 + threadIdx.x;   // < 262144
  wi16[i] = (f16)Wi[i];
  wh16[i] = (f16)Wh[i];
}

// ---------------- Fused 4-layer GEMM+scan, 16 seqs per block ----------------
#define HB_S 264   // f16 per h-column row (+8 pad -> 2-way banks, free)

__global__ __launch_bounds__(256, 1) void scan16_kernel(
    f16* __restrict__ buf16,          // [256 n][256 l][256 d] f16, in-place
    const f16* __restrict__ wi16,     // (4,256,256) f16
    const f16* __restrict__ wh16,     // (4,256,256) f16
    const float* __restrict__ ssc,    // (4,8,256)
    const float* __restrict__ bbv,    // (4,256)
    float* __restrict__ outh,         // (256,256,256) f32
    float* __restrict__ outl)         // (256,256) f32
{
  __shared__ __align__(16) f16 hbuf[2 * 16 * HB_S];   // 16.5 KB

  const int tid = threadIdx.x, lane = tid & 63, w = tid >> 6;
  const int n = lane & 15, q = lane >> 4;
  const int ng = blockIdx.x * 16 + n;          // this column's sequence
  const int e = ng & 7;
  f16* colb = buf16 + (size_t)ng * 65536;      // column n's [l][d] plane

  for (int layer = 0; layer < 4; ++layer) {
    // ---- resident W_hh fragments: 4 m-tiles x 8 k-chunks = 128 VGPRs ----
    f16x8 whh[4][8];
    f32x4 sv[4], bv[4];
    #pragma unroll
    for (int i = 0; i < 4; ++i) {
      const f16* wb = wh16 + layer * 65536 + (size_t)((w << 6) + (i << 4) + n) * 256 + (q << 3);
      #pragma unroll
      for (int kc = 0; kc < 8; ++kc)
        whh[i][kc] = *(const f16x8*)(wb + kc * 32);
      sv[i] = *(const f32x4*)(ssc + layer * 2048 + e * 256 + (w << 6) + (i << 4) + (q << 2));
      bv[i] = *(const f32x4*)(bbv + layer * 256 + (w << 6) + (i << 4) + (q << 2));
    }
    // zero h state (both parities)
    for (int i = tid; i < 2 * 16 * HB_S / 8; i += 256)
      ((f16x8*)hbuf)[i] = (f16x8){};
    __syncthreads();

    for (int c = 0; c < 32; ++c) {
      // ---- chunk GEMM: pre[i][lt] (f32x4) for 8 l-values, regs only ----
      f32x4 pre[4][8];
      #pragma unroll
      for (int i = 0; i < 4; ++i)
        #pragma unroll
        for (int lt = 0; lt < 8; ++lt) pre[i][lt] = (f32x4){0.f,0.f,0.f,0.f};

      #pragma unroll
      for (int half = 0; half < 2; ++half) {
        f16x8 wia[2][8];
        #pragma unroll
        for (int i2 = 0; i2 < 2; ++i2) {
          const f16* wb = wi16 + layer * 65536 +
              (size_t)((w << 6) + ((half * 2 + i2) << 4) + n) * 256 + (q << 3);
          #pragma unroll
          for (int kc = 0; kc < 8; ++kc)
            wia[i2][kc] = *(const f16x8*)(wb + kc * 32);
        }
        #pragma unroll
        for (int lt = 0; lt < 8; ++lt) {
          const f16* bb = colb + (size_t)((c << 3) + lt) * 256 + (q << 3);
          f16x8 Bg[8];
          #pragma unroll
          for (int kc = 0; kc < 8; ++kc) Bg[kc] = *(const f16x8*)(bb + kc * 32);
          #pragma unroll
          for (int kc = 0; kc < 8; ++kc) {
            pre[half * 2 + 0][lt] = __builtin_amdgcn_mfma_f32_16x16x32_f16(wia[0][kc], Bg[kc], pre[half * 2 + 0][lt], 0, 0, 0);
            pre[half * 2 + 1][lt] = __builtin_amdgcn_mfma_f32_16x16x32_f16(wia[1][kc], Bg[kc], pre[half * 2 + 1][lt], 0, 0, 0);
          }
        }
      }
      // epilogue: pre = pre * s[e][h] + b[h]  (row-indexed, per lane rows q*4+r)
      #pragma unroll
      for (int i = 0; i < 4; ++i)
        #pragma unroll
        for (int lt = 0; lt < 8; ++lt)
          #pragma unroll
          for (int r = 0; r < 4; ++r)
            pre[i][lt][r] = fmaf(pre[i][lt][r], sv[i][r], bv[i][r]);

      // ---- scan: 8 steps; acc IS pre[i][st] ----
      #pragma unroll
      for (int st = 0; st < 8; ++st) {
        const int l = (c << 3) + st;
        const f16* hb = hbuf + (l & 1) * (16 * HB_S) + n * HB_S + (q << 3);
        f16x8 Bf[8];
        #pragma unroll
        for (int kc = 0; kc < 8; ++kc) Bf[kc] = *(const f16x8*)(hb + kc * 32);
        #pragma unroll
        for (int kc = 0; kc < 8; ++kc) {
          pre[0][st] = __builtin_amdgcn_mfma_f32_16x16x32_f16(whh[0][kc], Bf[kc], pre[0][st], 0, 0, 0);
          pre[1][st] = __builtin_amdgcn_mfma_f32_16x16x32_f16(whh[1][kc], Bf[kc], pre[1][st], 0, 0, 0);
          pre[2][st] = __builtin_amdgcn_mfma_f32_16x16x32_f16(whh[2][kc], Bf[kc], pre[2][st], 0, 0, 0);
          pre[3][st] = __builtin_amdgcn_mfma_f32_16x16x32_f16(whh[3][kc], Bf[kc], pre[3][st], 0, 0, 0);
        }
        f16* hn = hbuf + ((l + 1) & 1) * (16 * HB_S) + n * HB_S;
        #pragma unroll
        for (int i = 0; i < 4; ++i) {
          f32x4 hv;
          #pragma unroll
          for (int r = 0; r < 4; ++r) hv[r] = tanh_fast(pre[i][st][r]);
          const int hrow = (w << 6) + (i << 4) + (q << 2);
          const f16x4 h4 = {(f16)hv[0], (f16)hv[1], (f16)hv[2], (f16)hv[3]};
          *(f16x4*)(hn + hrow) = h4;
          if (layer < 3) {
            *(f16x4*)(colb + (size_t)l * 256 + hrow) = h4;     // ys in place
          } else {
            *(f32x4*)(outh + ((size_t)ng * 256 + l) * 256 + hrow) = hv;
            if (l == 255) *(f32x4*)(outl + (size_t)ng * 256 + hrow) = hv;
          }
        }
        __syncthreads();
      }
    }
    __syncthreads();
  }
}

extern "C" void kernel_launch(void* const* d_in, const int* in_sizes, int n_in,
                              void* d_out, int out_size, void* d_ws, size_t ws_size,
                              hipStream_t stream) {
  const float* x      = (const float*)d_in[0];
  const float* conv_w = (const float*)d_in[1];
  const float* conv_b = (const float*)d_in[2];
  const float* ln_g   = (const float*)d_in[3];
  const float* ln_b   = (const float*)d_in[4];
  const float* W_ih   = (const float*)d_in[5];   // (4,256,256)
  const float* W_hh   = (const float*)d_in[6];   // (4,256,256)
  const float* r      = (const float*)d_in[7];   // (4,8,256)
  const float* s      = (const float*)d_in[8];   // (4,8,256)
  const float* bb     = (const float*)d_in[9];   // (4,256)

  float* outh = (float*)d_out;                   // (B,E,L,H)
  float* outl = outh + 16777216;                 // (B,E,H)

  // ws: [0,32M) buf16 f16 (lnb f32 aliases [0,8M), dead before xprep);
  //     [32,40M) cvb f32; [40,41M) wi16; [41,42M) wh16.  Total 42 MB.
  f16*   buf16 = (f16*)d_ws;
  float* lnb   = (float*)d_ws;
  float* cvb   = (float*)((char*)d_ws + (32u << 20));
  f16*   wi16  = (f16*)((char*)d_ws + (40u << 20));
  f16*   wh16  = (f16*)((char*)d_ws + (41u << 20));

  ln_kernel<<<8192, 256, 0, stream>>>(x, ln_g, ln_b, lnb);
  conv_kernel<<<8192, 256, 0, stream>>>(lnb, conv_w, conv_b, cvb);
  xprep_kernel<<<8192, 256, 0, stream>>>(cvb, r, buf16);
  wcvt_kernel<<<512, 512, 0, stream>>>(W_ih, W_hh, wi16, wh16);
  scan16_kernel<<<16, 256, 0, stream>>>(buf16, wi16, wh16, s, bb, outh, outl);
}